// Round 2
// baseline (456.776 us; speedup 1.0000x reference)
//
#include <hip/hip_runtime.h>
#include <hip/hip_bf16.h>

#define B_    8
#define N_    2048
#define FIN_  128
#define FOUT_ 64
#define ALPHA_ 0.2f
#define LN_EPS_ 1e-5f

// ---------------- kernel 1: h = x@W (f32), s1 = h@a1, s2 = h@a2 ----------------
// grid 256 blocks x 256 thr; each block: 64 rows. W + x-rows staged in LDS.
__global__ __launch_bounds__(256) void k_proj(
    const float* __restrict__ x,   // (B*N, 128) f32
    const float* __restrict__ W,   // (128, 64)  f32
    const float* __restrict__ a,   // (128,)     f32
    float* __restrict__ h,         // (B*N, 64)  f32 out
    float* __restrict__ s1, float* __restrict__ s2)
{
    __shared__ float Wl[FIN_ * FOUT_];   // 32 KB
    __shared__ float xl[64 * FIN_];      // 32 KB
    const int t = threadIdx.x;
    const int row0 = blockIdx.x * 64;

    {
        const float4* Wsrc = (const float4*)W;
        const float4* xsrc = (const float4*)&x[(size_t)row0 * FIN_];
        float4* Wdst = (float4*)Wl;
        float4* xdst = (float4*)xl;
        #pragma unroll
        for (int k = 0; k < 8; ++k) {
            Wdst[t + 256 * k] = Wsrc[t + 256 * k];
            xdst[t + 256 * k] = xsrc[t + 256 * k];
        }
    }
    __syncthreads();

    const int o  = t & 63;
    const int iq = t >> 6;
    const float a1 = a[o];
    const float a2 = a[FOUT_ + o];

    for (int rr = 0; rr < 16; ++rr) {
        int row = iq * 16 + rr;
        const float* xr = &xl[row * FIN_];
        float acc = 0.f;
        #pragma unroll
        for (int f = 0; f < FIN_; f += 4) {
            float4 xv = *(const float4*)&xr[f];   // broadcast within wave
            acc += xv.x * Wl[(f + 0) * FOUT_ + o];
            acc += xv.y * Wl[(f + 1) * FOUT_ + o];
            acc += xv.z * Wl[(f + 2) * FOUT_ + o];
            acc += xv.w * Wl[(f + 3) * FOUT_ + o];
        }
        h[(size_t)(row0 + row) * FOUT_ + o] = acc;
        float v1 = acc * a1, v2 = acc * a2;
        #pragma unroll
        for (int d = 32; d; d >>= 1) {
            v1 += __shfl_xor(v1, d);
            v2 += __shfl_xor(v2, d);
        }
        if (o == 0) { s1[row0 + row] = v1; s2[row0 + row] = v2; }
    }
}

// ---------------- kernel 2: masked softmax attention + PV + LN + ELU ----------------
// grid = B * (N/TI) = 512 blocks x 256 thr. TI=32 query rows/block, TJ=128 key tile.
// m_i = lrelu(s1_i + max_j s2_j) is an upper bound on every masked score
// (lrelu monotone) -> single pass, no rescaling; masked entries get w=0.
__global__ __launch_bounds__(256) void k_attn(
    const int* __restrict__ adj,            // (B, N, N) int32
    const float* __restrict__ h,            // (B*N, 64) f32
    const float* __restrict__ s1g,
    const float* __restrict__ s2g,
    const float* __restrict__ gamma,
    const float* __restrict__ beta,
    float* __restrict__ out)                // (B*N, 64) f32
{
    const int TI = 32, TJ = 128;
    __shared__ float hl[TJ * FOUT_];   // 32 KB
    __shared__ float wl[TI * TJ];      // 16 KB
    __shared__ float s2l[TJ];
    __shared__ float s1l[TI], ml[TI], ll[TI];
    __shared__ float red[4];

    const int t  = threadIdx.x;
    const int b  = blockIdx.x >> 6;          // 64 i-tiles per batch
    const int i0 = (blockIdx.x & 63) * TI;
    const size_t rowbase = (size_t)b * N_;

    if (t < TI) { s1l[t] = s1g[rowbase + i0 + t]; ll[t] = 0.f; }

    // per-batch max of s2 (upper bound for softmax max)
    float mx = -3.0e38f;
    #pragma unroll
    for (int k = 0; k < 8; ++k) mx = fmaxf(mx, s2g[rowbase + t + 256 * k]);
    #pragma unroll
    for (int d = 32; d; d >>= 1) mx = fmaxf(mx, __shfl_xor(mx, d));
    if ((t & 63) == 0) red[t >> 6] = mx;
    __syncthreads();
    {
        float smax = fmaxf(fmaxf(red[0], red[1]), fmaxf(red[2], red[3]));
        if (t < TI) {
            float v = s1l[t] + smax;
            ml[t] = v > 0.f ? v : ALPHA_ * v;
        }
    }

    const int o  = t & 63;
    const int iq = t >> 6;
    float acc[8];
    #pragma unroll
    for (int r = 0; r < 8; ++r) acc[r] = 0.f;

    const size_t adjrow0 = ((size_t)b * N_ + i0) * N_;

    for (int j0 = 0; j0 < N_; j0 += TJ) {
        __syncthreads();   // protect hl/wl reuse + (first iter) ml/s1l visibility
        // stage h tile: 128x64 f32, float4-coalesced
        {
            const float4* hsrc = (const float4*)&h[(rowbase + j0) * FOUT_];
            float4* hdst = (float4*)hl;
            #pragma unroll
            for (int k = 0; k < 8; ++k) hdst[t + 256 * k] = hsrc[t + 256 * k];
        }
        if (t < TJ) s2l[t] = s2g[rowbase + j0 + t];
        __syncthreads();

        // w tile: 32x128 entries; adj streamed coalesced from HBM (read once)
        #pragma unroll
        for (int k = 0; k < 16; ++k) {
            int e = t + 256 * k;
            int j = e & (TJ - 1), i = e >> 7;
            int av = adj[adjrow0 + (size_t)i * N_ + j0 + j];
            float ev = s1l[i] + s2l[j];
            ev = ev > 0.f ? ev : ALPHA_ * ev;
            wl[e] = (av > 0) ? __expf(ev - ml[i]) : 0.f;
        }
        __syncthreads();

        // l_i += row-sum of w tile (8 threads per row, shuffle-combined)
        {
            int i = t >> 3, p = t & 7;
            float s = 0.f;
            #pragma unroll
            for (int k = 0; k < 16; ++k) s += wl[i * TJ + p + 8 * k];
            #pragma unroll
            for (int d = 4; d; d >>= 1) s += __shfl_down(s, d);
            if (p == 0) ll[i] += s;
        }

        // PV matmul: thread (o, iq) accumulates rows i = iq*8+r.
        // wl reads: same addr across the wave -> broadcast (free);
        // hl reads: 64 consecutive f32 -> 2 lanes/bank (free).
        #pragma unroll 4
        for (int j = 0; j < TJ; j += 4) {
            float hv0 = hl[(j + 0) * FOUT_ + o];
            float hv1 = hl[(j + 1) * FOUT_ + o];
            float hv2 = hl[(j + 2) * FOUT_ + o];
            float hv3 = hl[(j + 3) * FOUT_ + o];
            #pragma unroll
            for (int r = 0; r < 8; ++r) {
                float4 wv = *(const float4*)&wl[(iq * 8 + r) * TJ + j];
                acc[r] += wv.x * hv0 + wv.y * hv1 + wv.z * hv2 + wv.w * hv3;
            }
        }
    }

    __syncthreads();
    const float g  = gamma[o];
    const float be = beta[o];
    #pragma unroll
    for (int r = 0; r < 8; ++r) {
        int i = iq * 8 + r;
        float hp = acc[r] / ll[i];
        float mu = hp;
        #pragma unroll
        for (int d = 32; d; d >>= 1) mu += __shfl_xor(mu, d);
        mu *= (1.f / 64.f);
        float dv = hp - mu;
        float var = dv * dv;
        #pragma unroll
        for (int d = 32; d; d >>= 1) var += __shfl_xor(var, d);
        var *= (1.f / 64.f);
        float y = dv * rsqrtf(var + LN_EPS_) * g + be;
        float e = y > 0.f ? y : (__expf(y) - 1.f);
        out[(rowbase + i0 + i) * FOUT_ + o] = e;
    }
}

extern "C" void kernel_launch(void* const* d_in, const int* in_sizes, int n_in,
                              void* d_out, int out_size, void* d_ws, size_t ws_size,
                              hipStream_t stream) {
    const float* x     = (const float*)d_in[0];
    const int*   adj   = (const int*)d_in[1];
    const float* W     = (const float*)d_in[2];
    const float* a     = (const float*)d_in[3];
    const float* gamma = (const float*)d_in[4];
    const float* beta  = (const float*)d_in[5];
    float* out = (float*)d_out;

    float* h  = (float*)d_ws;                       // 8*2048*64 f32 = 4 MB
    float* s1 = h + (size_t)B_ * N_ * FOUT_;        // 64 KB
    float* s2 = s1 + (size_t)B_ * N_;               // 64 KB

    k_proj<<<256, 256, 0, stream>>>(x, W, a, h, s1, s2);
    k_attn<<<B_ * (N_ / 32), 256, 0, stream>>>(adj, h, s1, s2, gamma, beta, out);
}

// Round 4
// 226.357 us; speedup vs baseline: 2.0179x; 2.0179x over previous
//
#include <hip/hip_runtime.h>
#include <hip/hip_bf16.h>

#define B_    8
#define N_    2048
#define FIN_  128
#define FOUT_ 64
#define ALPHA_ 0.2f
#define LN_EPS_ 1e-5f

typedef __attribute__((ext_vector_type(8))) short short8;
typedef __attribute__((ext_vector_type(4))) float f32x4;

__device__ __forceinline__ short f2bf(float f) {
    __hip_bfloat16 h = __float2bfloat16(f);          // RNE
    return *reinterpret_cast<short*>(&h);
}
__device__ __forceinline__ float bf2f(short s) {
    return __uint_as_float(((unsigned)(unsigned short)s) << 16);
}

// ============ kernel 1: h = x@W (bf16 MFMA) -> h_T bf16; s1 = x@(W a1), s2 = x@(W a2) ============
// 256 blocks x 256 thr; block = 64 rows; wave = 16 rows (1 M-tile), 4 N-tiles.
__global__ __launch_bounds__(256) void k_proj(
    const float* __restrict__ x,    // (B*N, 128)
    const float* __restrict__ W,    // (128, 64)
    const float* __restrict__ a,    // (128,)
    unsigned short* __restrict__ hT,// (B*64, 2048) bf16 bits: h_T[b][o][j]
    float* __restrict__ s1, float* __restrict__ s2)
{
    __shared__ short Wb[16 * 64 * 8];     // 16 KB: B-frags, u = ks*4+nt
    __shared__ float Wa1l[FIN_], Wa2l[FIN_];

    const int t = threadIdx.x;
    const int row0 = blockIdx.x * 64;
    const int b   = row0 >> 11;
    const int ib0 = row0 & (N_ - 1);

    // stage W as bf16 B-fragments: Wb[(ks*4+nt)*64+ln] <- W[k=ks*32+(ln>>4)*8+jj][n=nt*16+(ln&15)]
    // 16 frag-sets x 64 lanes = 1024 chunks -> c < 4  (R3 bug: c<2 left ks=2,3 unstaged)
    #pragma unroll
    for (int c = 0; c < 4; ++c) {
        int g = t + 256 * c;
        int u = g >> 6, ln = g & 63;
        int ks = u >> 2, nt = u & 3;
        int n  = nt * 16 + (ln & 15);
        int k0 = ks * 32 + (ln >> 4) * 8;
        short8 v;
        #pragma unroll
        for (int jj = 0; jj < 8; ++jj) v[jj] = f2bf(W[(k0 + jj) * FOUT_ + n]);
        *(short8*)&Wb[g * 8] = v;
    }
    // Wa1 = W@a1, Wa2 = W@a2 (128-vectors)
    if (t < FIN_) {
        float a1 = 0.f, a2 = 0.f;
        #pragma unroll
        for (int n = 0; n < FOUT_; n += 4) {
            float4 wv  = *(const float4*)&W[t * FOUT_ + n];
            float4 av1 = *(const float4*)&a[n];
            float4 av2 = *(const float4*)&a[FOUT_ + n];
            a1 += wv.x * av1.x + wv.y * av1.y + wv.z * av1.z + wv.w * av1.w;
            a2 += wv.x * av2.x + wv.y * av2.y + wv.z * av2.z + wv.w * av2.w;
        }
        Wa1l[t] = a1; Wa2l[t] = a2;
    }
    __syncthreads();

    const int wave = t >> 6, lane = t & 63;
    const int m = lane & 15, quad = lane >> 4;
    const int row = row0 + wave * 16 + m;

    // A-frags from global x + s1/s2 partials (f32)
    short8 fa[4];
    float s1p = 0.f, s2p = 0.f;
    #pragma unroll
    for (int ks = 0; ks < 4; ++ks) {
        int k0 = ks * 32 + quad * 8;
        float4 x0 = *(const float4*)&x[(size_t)row * FIN_ + k0];
        float4 x1 = *(const float4*)&x[(size_t)row * FIN_ + k0 + 4];
        float xs[8] = {x0.x, x0.y, x0.z, x0.w, x1.x, x1.y, x1.z, x1.w};
        short8 v;
        #pragma unroll
        for (int jj = 0; jj < 8; ++jj) {
            v[jj] = f2bf(xs[jj]);
            s1p += xs[jj] * Wa1l[k0 + jj];
            s2p += xs[jj] * Wa2l[k0 + jj];
        }
        fa[ks] = v;
    }
    s1p += __shfl_xor(s1p, 16); s1p += __shfl_xor(s1p, 32);
    s2p += __shfl_xor(s2p, 16); s2p += __shfl_xor(s2p, 32);
    if (lane < 16) {
        s1[row0 + wave * 16 + lane] = s1p;
        s2[row0 + wave * 16 + lane] = s2p;
    }

    f32x4 acc[4];
    #pragma unroll
    for (int nt = 0; nt < 4; ++nt) acc[nt] = (f32x4){0.f, 0.f, 0.f, 0.f};
    #pragma unroll
    for (int ks = 0; ks < 4; ++ks) {
        #pragma unroll
        for (int nt = 0; nt < 4; ++nt) {
            short8 fb = *(short8*)&Wb[((ks * 4 + nt) * 64 + lane) * 8];
            acc[nt] = __builtin_amdgcn_mfma_f32_16x16x32_bf16(fa[ks], fb, acc[nt], 0, 0, 0);
        }
    }
    // store h^T as bf16: C layout col(n)=lane&15, row(m)=quad*4+reg
    #pragma unroll
    for (int nt = 0; nt < 4; ++nt) {
        int o  = nt * 16 + m;
        int ib = ib0 + wave * 16 + quad * 4;
        ushort4 hv;
        hv.x = (unsigned short)f2bf(acc[nt][0]);
        hv.y = (unsigned short)f2bf(acc[nt][1]);
        hv.z = (unsigned short)f2bf(acc[nt][2]);
        hv.w = (unsigned short)f2bf(acc[nt][3]);
        *(ushort4*)&hT[(size_t)(b * 64 + o) * N_ + ib] = hv;
    }
}

// ============ kernel 2: masked softmax attention (rank-1 scores) + MFMA PV + LN + ELU ============
// grid = B*(N/16) = 1024 blocks x 256 thr. TI=16 rows, TJ=128 key tile.
// m_i = lrelu(s1_i + max_j s2_j) upper-bounds every masked score -> single pass, no rescale.
__global__ __launch_bounds__(256) void k_attn(
    const int* __restrict__ adj,
    const unsigned short* __restrict__ hT,   // h_T[b][o][j] bf16 bits
    const float* __restrict__ s1g, const float* __restrict__ s2g,
    const float* __restrict__ gamma, const float* __restrict__ beta,
    float* __restrict__ out)
{
    __shared__ short Hb[16 * 64 * 8];   // 16 KB: h B-frags, u = ks*4+nt
    __shared__ short Wf[4 * 64 * 8];    // 4 KB: w A-frags, [ks][lane][8]
    __shared__ float s2l[128];
    __shared__ float s1l[16], ml[16];
    __shared__ float lp[4][16];
    __shared__ float hp[16 * 64];       // 4 KB
    __shared__ float red[4];

    const int t = threadIdx.x;
    const int wave = t >> 6, lane = t & 63;
    const int i_ = lane & 15, quad = lane >> 4;
    const int b  = blockIdx.x >> 7;
    const int i0 = (blockIdx.x & 127) * 16;
    const size_t sbase  = (size_t)b * N_;
    const size_t hTbase = (size_t)b * 64 * N_;

    // per-batch max of s2
    float mx = -3.0e38f;
    #pragma unroll
    for (int k = 0; k < 8; ++k) mx = fmaxf(mx, s2g[sbase + t + 256 * k]);
    #pragma unroll
    for (int d = 32; d; d >>= 1) mx = fmaxf(mx, __shfl_xor(mx, d));
    if (lane == 0) red[wave] = mx;
    __syncthreads();
    {
        float smax = fmaxf(fmaxf(red[0], red[1]), fmaxf(red[2], red[3]));
        if (t < 16) {
            float s1v = s1g[sbase + i0 + t];
            s1l[t] = s1v;
            float v = s1v + smax;
            ml[t] = fmaxf(v, ALPHA_ * v);
        }
    }

    f32x4 acc = (f32x4){0.f, 0.f, 0.f, 0.f};
    float lpart = 0.f;   // per-thread: row i_, k-slice ks=wave, summed across tiles

    for (int j0 = 0; j0 < N_; j0 += 128) {
        __syncthreads();   // prev-iter frag reads done before overwrite (+ s1l/ml vis on iter 0)
        // stage h B-frags: 16B contiguous reads from h_T
        #pragma unroll
        for (int c = 0; c < 4; ++c) {
            int g = t + 256 * c;
            int u = g >> 6, ln = g & 63;
            int ks = u >> 2, nt = u & 3;
            int o  = nt * 16 + (ln & 15);
            int jr = ks * 32 + (ln >> 4) * 8;
            short8 v = *(const short8*)&hT[hTbase + (size_t)o * N_ + j0 + jr];
            *(short8*)&Hb[g * 8] = v;
        }
        if (t < 128) s2l[t] = s2g[sbase + j0 + t];
        __syncthreads();

        // w A-frag: thread t -> (ks=wave, i=i_, 8 consecutive j)
        {
            int jr = wave * 32 + quad * 8;
            const int* ap = &adj[(sbase + i0 + i_) * N_ + j0 + jr];
            int4 a0 = *(const int4*)ap;
            int4 a1 = *(const int4*)(ap + 4);
            int am[8] = {a0.x, a0.y, a0.z, a0.w, a1.x, a1.y, a1.z, a1.w};
            float s1v = s1l[i_], mv = ml[i_];
            float sum = 0.f;
            short8 wv;
            #pragma unroll
            for (int jj = 0; jj < 8; ++jj) {
                float ev = s1v + s2l[jr + jj];
                ev = fmaxf(ev, ALPHA_ * ev);
                float w = (am[jj] > 0) ? __expf(ev - mv) : 0.f;
                short ws = f2bf(w);
                wv[jj] = ws;
                sum += bf2f(ws);      // l consistent with bf16-rounded numerator
            }
            *(short8*)&Wf[t * 8] = wv;
            lpart += sum;
        }
        __syncthreads();

        // PV: wave owns N-tile nt=wave; 4 MFMA per tile
        #pragma unroll
        for (int ks = 0; ks < 4; ++ks) {
            short8 fa = *(short8*)&Wf[(ks * 64 + lane) * 8];
            short8 fb = *(short8*)&Hb[((ks * 4 + wave) * 64 + lane) * 8];
            acc = __builtin_amdgcn_mfma_f32_16x16x32_bf16(fa, fb, acc, 0, 0, 0);
        }
    }

    // l: reduce per-thread partials over quads, combine 4 k-slices via LDS
    lpart += __shfl_xor(lpart, 16);
    lpart += __shfl_xor(lpart, 32);
    if (lane < 16) lp[wave][lane] = lpart;
    __syncthreads();

    // h' = acc / l into LDS (C layout: n=lane&15 -> col = wave*16+i_, m=quad*4+reg -> row)
    {
        int col = wave * 16 + i_;
        #pragma unroll
        for (int reg = 0; reg < 4; ++reg) {
            int r = quad * 4 + reg;
            float l = lp[0][r] + lp[1][r] + lp[2][r] + lp[3][r];
            hp[r * 64 + col] = acc[reg] / l;
        }
    }
    __syncthreads();

    // LayerNorm over o (=lane) + ELU, coalesced store
    {
        int o = lane;
        float g  = gamma[o];
        float be = beta[o];
        #pragma unroll
        for (int rr = 0; rr < 4; ++rr) {
            int i = wave * 4 + rr;
            float v = hp[i * 64 + o];
            float mu = v;
            #pragma unroll
            for (int d = 32; d; d >>= 1) mu += __shfl_xor(mu, d);
            mu *= (1.f / 64.f);
            float dv = v - mu;
            float var = dv * dv;
            #pragma unroll
            for (int d = 32; d; d >>= 1) var += __shfl_xor(var, d);
            var *= (1.f / 64.f);
            float y = dv * rsqrtf(var + LN_EPS_) * g + be;
            out[(sbase + i0 + i) * FOUT_ + o] = y > 0.f ? y : __expf(y) - 1.f;
        }
    }
}

extern "C" void kernel_launch(void* const* d_in, const int* in_sizes, int n_in,
                              void* d_out, int out_size, void* d_ws, size_t ws_size,
                              hipStream_t stream) {
    const float* x     = (const float*)d_in[0];
    const int*   adj   = (const int*)d_in[1];
    const float* W     = (const float*)d_in[2];
    const float* a     = (const float*)d_in[3];
    const float* gamma = (const float*)d_in[4];
    const float* beta  = (const float*)d_in[5];
    float* out = (float*)d_out;

    unsigned short* hT = (unsigned short*)d_ws;                 // 2 MB bf16
    float* s1 = (float*)((char*)d_ws + (size_t)B_ * 64 * N_ * 2);
    float* s2 = s1 + (size_t)B_ * N_;

    k_proj<<<256, 256, 0, stream>>>(x, W, a, hT, s1, s2);
    k_attn<<<B_ * (N_ / 16), 256, 0, stream>>>(adj, hT, s1, s2, gamma, beta, out);
}

// Round 5
// 219.789 us; speedup vs baseline: 2.0782x; 1.0299x over previous
//
#include <hip/hip_runtime.h>
#include <hip/hip_bf16.h>

#define B_    8
#define N_    2048
#define FIN_  128
#define FOUT_ 64
#define ALPHA_ 0.2f
#define LN_EPS_ 1e-5f

typedef __attribute__((ext_vector_type(8))) short short8;
typedef __attribute__((ext_vector_type(4))) float f32x4;

__device__ __forceinline__ short f2bf(float f) {
    __hip_bfloat16 h = __float2bfloat16(f);          // RNE
    return *reinterpret_cast<short*>(&h);
}
__device__ __forceinline__ float bf2f(short s) {
    return __uint_as_float(((unsigned)(unsigned short)s) << 16);
}

// ============ kernel 0: precompute W bf16 B-fragments + Wa1/Wa2 (1 block) ============
__global__ __launch_bounds__(256) void k_prep(
    const float* __restrict__ W, const float* __restrict__ a,
    short* __restrict__ Wbf, float* __restrict__ Wa1g, float* __restrict__ Wa2g)
{
    const int t = threadIdx.x;
    #pragma unroll
    for (int c = 0; c < 4; ++c) {
        int g = t + 256 * c;
        int u = g >> 6, ln = g & 63;
        int ks = u >> 2, nt = u & 3;
        int n  = nt * 16 + (ln & 15);
        int k0 = ks * 32 + (ln >> 4) * 8;
        short8 v;
        #pragma unroll
        for (int jj = 0; jj < 8; ++jj) v[jj] = f2bf(W[(k0 + jj) * FOUT_ + n]);
        *(short8*)&Wbf[g * 8] = v;
    }
    if (t < FIN_) {
        float a1 = 0.f, a2 = 0.f;
        #pragma unroll
        for (int n = 0; n < FOUT_; n += 4) {
            float4 wv  = *(const float4*)&W[t * FOUT_ + n];
            float4 av1 = *(const float4*)&a[n];
            float4 av2 = *(const float4*)&a[FOUT_ + n];
            a1 += wv.x * av1.x + wv.y * av1.y + wv.z * av1.z + wv.w * av1.w;
            a2 += wv.x * av2.x + wv.y * av2.y + wv.z * av2.z + wv.w * av2.w;
        }
        Wa1g[t] = a1; Wa2g[t] = a2;
    }
}

// ============ kernel 1: h = x@W (bf16 MFMA) -> h_T bf16; s1, s2 ============
// 512 blocks x 256 thr; block = 32 rows; wave: M-tile mt=wave&1, N-tiles {nt0,nt0+1}.
__global__ __launch_bounds__(256) void k_proj(
    const float* __restrict__ x,
    const short* __restrict__ Wbf,          // precomputed B-frags (L2-resident)
    const float* __restrict__ Wa1g, const float* __restrict__ Wa2g,
    unsigned short* __restrict__ hT,        // (B*64, 2048) bf16 bits: h_T[b][o][j]
    float* __restrict__ s1, float* __restrict__ s2)
{
    __shared__ float Wa1l[FIN_], Wa2l[FIN_];
    const int t = threadIdx.x;
    const int row0 = blockIdx.x * 32;
    const int b   = row0 >> 11;
    const int ib0 = row0 & (N_ - 1);

    if (t < FIN_) { Wa1l[t] = Wa1g[t]; Wa2l[t] = Wa2g[t]; }
    __syncthreads();

    const int wave = t >> 6, lane = t & 63;
    const int m = lane & 15, quad = lane >> 4;
    const int mt = wave & 1, nt0 = (wave >> 1) * 2;
    const int row = row0 + mt * 16 + m;

    short8 fa[4];
    float s1p = 0.f, s2p = 0.f;
    #pragma unroll
    for (int ks = 0; ks < 4; ++ks) {
        int k0 = ks * 32 + quad * 8;
        float4 x0 = *(const float4*)&x[(size_t)row * FIN_ + k0];
        float4 x1 = *(const float4*)&x[(size_t)row * FIN_ + k0 + 4];
        float xs[8] = {x0.x, x0.y, x0.z, x0.w, x1.x, x1.y, x1.z, x1.w};
        short8 v;
        #pragma unroll
        for (int jj = 0; jj < 8; ++jj) {
            v[jj] = f2bf(xs[jj]);
            s1p += xs[jj] * Wa1l[k0 + jj];
            s2p += xs[jj] * Wa2l[k0 + jj];
        }
        fa[ks] = v;
    }
    s1p += __shfl_xor(s1p, 16); s1p += __shfl_xor(s1p, 32);
    s2p += __shfl_xor(s2p, 16); s2p += __shfl_xor(s2p, 32);
    if (wave < 2 && lane < 16) {            // wave 0 -> mt 0 rows, wave 1 -> mt 1 rows
        s1[row0 + wave * 16 + lane] = s1p;
        s2[row0 + wave * 16 + lane] = s2p;
    }

    f32x4 acc[2];
    acc[0] = (f32x4){0.f, 0.f, 0.f, 0.f};
    acc[1] = (f32x4){0.f, 0.f, 0.f, 0.f};
    #pragma unroll
    for (int ks = 0; ks < 4; ++ks) {
        #pragma unroll
        for (int q = 0; q < 2; ++q) {
            short8 fb = *(const short8*)&Wbf[((ks * 4 + nt0 + q) * 64 + lane) * 8];
            acc[q] = __builtin_amdgcn_mfma_f32_16x16x32_bf16(fa[ks], fb, acc[q], 0, 0, 0);
        }
    }
    #pragma unroll
    for (int q = 0; q < 2; ++q) {
        int o  = (nt0 + q) * 16 + m;
        int ib = ib0 + mt * 16 + quad * 4;
        ushort4 hv;
        hv.x = (unsigned short)f2bf(acc[q][0]);
        hv.y = (unsigned short)f2bf(acc[q][1]);
        hv.z = (unsigned short)f2bf(acc[q][2]);
        hv.w = (unsigned short)f2bf(acc[q][3]);
        *(ushort4*)&hT[(size_t)(b * 64 + o) * N_ + ib] = hv;
    }
}

// ============ kernel 2: masked softmax attention + MFMA PV + LN + ELU ============
// grid = B*(N/16) = 1024 blocks x 256 thr; ~29 KB LDS -> 4 blocks/CU co-resident.
// Pipelined: adj reg-prefetch crosses the loop-top raw barrier (lgkmcnt-only, no
// vmcnt drain); Hb global loads issued at tile top, LDS-written after w-phase.
__global__ __launch_bounds__(256) void k_attn(
    const int* __restrict__ adj,
    const unsigned short* __restrict__ hT,
    const float* __restrict__ s1g, const float* __restrict__ s2g,
    const float* __restrict__ gamma, const float* __restrict__ beta,
    float* __restrict__ out)
{
    __shared__ short Hb[16 * 64 * 8];          // 16 KB: h B-frags
    __shared__ __align__(16) char pool[4096];  // Wf (4 KB) aliased with hp (4 KB)
    __shared__ float s2l[N_];                  // 8 KB: full-batch s2
    __shared__ float s1l[16], ml[16];
    __shared__ float lp[4][16];
    __shared__ float red[4];
    short* Wf = (short*)pool;                  // [4*64*8] w A-frags
    float* hp = (float*)pool;                  // [16*64] epilogue h'

    const int t = threadIdx.x;
    const int wave = t >> 6, lane = t & 63;
    const int i_ = lane & 15, quad = lane >> 4;
    const int b  = blockIdx.x >> 7;
    const int i0 = (blockIdx.x & 127) * 16;
    const size_t sbase  = (size_t)b * N_;
    const size_t hTbase = (size_t)b * 64 * N_;

    // prologue: stage full s2 (2048 f32) + per-batch max
    float4 v0 = *(const float4*)&s2g[sbase + 4 * t];
    float4 v1 = *(const float4*)&s2g[sbase + 4 * (t + 256)];
    *(float4*)&s2l[4 * t] = v0;
    *(float4*)&s2l[4 * (t + 256)] = v1;
    float mx = fmaxf(fmaxf(fmaxf(v0.x, v0.y), fmaxf(v0.z, v0.w)),
                     fmaxf(fmaxf(v1.x, v1.y), fmaxf(v1.z, v1.w)));
    #pragma unroll
    for (int d = 32; d; d >>= 1) mx = fmaxf(mx, __shfl_xor(mx, d));
    if (lane == 0) red[wave] = mx;
    __syncthreads();
    {
        float smax = fmaxf(fmaxf(red[0], red[1]), fmaxf(red[2], red[3]));
        if (t < 16) {
            float s1v = s1g[sbase + i0 + t];
            s1l[t] = s1v;
            float v = s1v + smax;
            ml[t] = fmaxf(v, ALPHA_ * v);
        }
    }

    const int jr = wave * 32 + quad * 8;       // this thread's j-slice within a tile
    const int* adjrow = &adj[(sbase + i0 + i_) * N_ + jr];

    // prefetch adj tile 0
    int4 pa0 = *(const int4*)&adjrow[0];
    int4 pa1 = *(const int4*)&adjrow[4];

    f32x4 acc = (f32x4){0.f, 0.f, 0.f, 0.f};
    float lpart = 0.f;

    for (int tile = 0; tile < 16; ++tile) {
        const int j0 = tile * 128;
        // top barrier: prev PV ds_reads drained (lgkm only; adj prefetch stays in flight)
        asm volatile("s_waitcnt lgkmcnt(0)\n\ts_barrier" ::: "memory");

        // issue Hb global loads (consumed after w-phase)
        short8 hv[4];
        #pragma unroll
        for (int c = 0; c < 4; ++c) {
            int u  = c * 4 + wave;             // frag-set; wave-uniform
            int ks = u >> 2, nt = u & 3;
            int o  = nt * 16 + i_;
            int j2 = ks * 32 + quad * 8;
            hv[c] = *(const short8*)&hT[hTbase + (size_t)o * N_ + j0 + j2];
        }

        // w-phase from prefetched adj regs + resident s2l
        {
            int am[8] = {pa0.x, pa0.y, pa0.z, pa0.w, pa1.x, pa1.y, pa1.z, pa1.w};
            float s1v = s1l[i_], mv = ml[i_];
            float sum = 0.f;
            short8 wv;
            #pragma unroll
            for (int jj = 0; jj < 8; ++jj) {
                float ev = s1v + s2l[j0 + jr + jj];
                ev = fmaxf(ev, ALPHA_ * ev);
                float w = (am[jj] > 0) ? __expf(ev - mv) : 0.f;
                short ws = f2bf(w);
                wv[jj] = ws;
                sum += bf2f(ws);               // l consistent with bf16-rounded numerator
            }
            *(short8*)&Wf[t * 8] = wv;
            lpart += sum;
        }

        // prefetch adj for next tile (wraps to 0 on last iter; harmless)
        {
            int j0n = (j0 + 128) & (N_ - 1);
            pa0 = *(const int4*)&adjrow[j0n];
            pa1 = *(const int4*)&adjrow[j0n + 4];
        }

        // write Hb (vmcnt waited here by compiler)
        #pragma unroll
        for (int c = 0; c < 4; ++c)
            *(short8*)&Hb[((c * 4 + wave) * 64 + lane) * 8] = hv[c];

        __syncthreads();                       // Hb + Wf visible

        // PV: wave owns N-tile nt=wave; 4 MFMA
        #pragma unroll
        for (int ks = 0; ks < 4; ++ks) {
            short8 fa = *(short8*)&Wf[(ks * 64 + lane) * 8];
            short8 fb = *(short8*)&Hb[((ks * 4 + wave) * 64 + lane) * 8];
            acc = __builtin_amdgcn_mfma_f32_16x16x32_bf16(fa, fb, acc, 0, 0, 0);
        }
    }

    // l: reduce per-thread partials over quads, combine 4 k-slices
    lpart += __shfl_xor(lpart, 16);
    lpart += __shfl_xor(lpart, 32);
    if (lane < 16) lp[wave][lane] = lpart;
    __syncthreads();                           // also: last PV reads done before hp aliases Wf

    {
        int col = wave * 16 + i_;              // = o
        #pragma unroll
        for (int reg = 0; reg < 4; ++reg) {
            int r = quad * 4 + reg;            // = i
            float l = lp[0][r] + lp[1][r] + lp[2][r] + lp[3][r];
            hp[r * 64 + col] = acc[reg] / l;
        }
    }
    __syncthreads();

    {
        int o = lane;
        float g  = gamma[o];
        float be = beta[o];
        #pragma unroll
        for (int rr = 0; rr < 4; ++rr) {
            int i = wave * 4 + rr;
            float v = hp[i * 64 + o];
            float mu = v;
            #pragma unroll
            for (int d = 32; d; d >>= 1) mu += __shfl_xor(mu, d);
            mu *= (1.f / 64.f);
            float dv = v - mu;
            float var = dv * dv;
            #pragma unroll
            for (int d = 32; d; d >>= 1) var += __shfl_xor(var, d);
            var *= (1.f / 64.f);
            float y = dv * rsqrtf(var + LN_EPS_) * g + be;
            out[(sbase + i0 + i) * FOUT_ + o] = y > 0.f ? y : __expf(y) - 1.f;
        }
    }
}

extern "C" void kernel_launch(void* const* d_in, const int* in_sizes, int n_in,
                              void* d_out, int out_size, void* d_ws, size_t ws_size,
                              hipStream_t stream) {
    const float* x     = (const float*)d_in[0];
    const int*   adj   = (const int*)d_in[1];
    const float* W     = (const float*)d_in[2];
    const float* a     = (const float*)d_in[3];
    const float* gamma = (const float*)d_in[4];
    const float* beta  = (const float*)d_in[5];
    float* out = (float*)d_out;

    char* ws = (char*)d_ws;
    unsigned short* hT = (unsigned short*)ws;                      // 2 MB
    float* s1   = (float*)(ws + (size_t)B_ * 64 * N_ * 2);         // 64 KB
    float* s2   = s1 + (size_t)B_ * N_;                            // 64 KB
    short* Wbf  = (short*)(s2 + (size_t)B_ * N_);                  // 16 KB
    float* Wa1g = (float*)(Wbf + 16 * 64 * 8);                     // 512 B
    float* Wa2g = Wa1g + FIN_;                                     // 512 B

    k_prep<<<1, 256, 0, stream>>>(W, a, Wbf, Wa1g, Wa2g);
    k_proj<<<512, 256, 0, stream>>>(x, Wbf, Wa1g, Wa2g, hT, s1, s2);
    k_attn<<<B_ * (N_ / 16), 256, 0, stream>>>(adj, hT, s1, s2, gamma, beta, out);
}